// Round 13
// baseline (317.620 us; speedup 1.0000x reference)
//
#include <hip/hip_runtime.h>

// ---------------------------------------------------------------------------
// FullAttention (bidirectional attention) on MI355X.
// B=16, P=4096, Q=512, D_IN=512, H=256, DR=256. Outputs fp32.
// Score path uses double-bf16 (hi+lo) splits: 3-pass MFMA per GEMM.
// prep_mega: ugemm<0> + ugemm<1> + rep/rep_p transposes IN ONE LAUNCH.
// dir2: 1024 threads / 16 waves, 128-row P-tile (2 blocks/CU = 32 waves/CU),
// 1-barrier dbuf B staging (t<512), A-frags from L2, phase 2 in two 64-row
// passes (probs[64][520] overlay, 1 rT frag -> 4 MFMA per k0 per wave).
// launch_bounds min-waves kept low: round-8 showed tight caps spill acc.
// dir1 = exp(S^T-M) @ rep_p, split-4 over p, deep register prefetch (T14).
// ---------------------------------------------------------------------------

typedef float  f32x4   __attribute__((ext_vector_type(4)));
typedef float  float4v __attribute__((ext_vector_type(4)));
typedef short  short8v __attribute__((ext_vector_type(8)));
typedef unsigned short us4 __attribute__((ext_vector_type(4)));
typedef unsigned short us8v __attribute__((ext_vector_type(8)));

#define MFMA16(a,b,c) __builtin_amdgcn_mfma_f32_16x16x32_bf16((a),(b),(c),0,0,0)

__device__ __forceinline__ unsigned short f2bf(float f) {
  unsigned int u = __builtin_bit_cast(unsigned int, f);
  u += 0x7FFFu + ((u >> 16) & 1u);           // round-to-nearest-even
  return (unsigned short)(u >> 16);
}
__device__ __forceinline__ float bf2f(unsigned short h) {
  unsigned int u = (unsigned int)h << 16;
  return __builtin_bit_cast(float, u);
}
__device__ __forceinline__ void split2(float v, unsigned short& h, unsigned short& l) {
  h = f2bf(v);
  l = f2bf(v - bf2f(h));
}
__device__ __forceinline__ unsigned short enc16(float a, float cm) {
  float x = (a - cm + 20.f) * 3276.8f + 0.5f;
  x = fminf(fmaxf(x, 0.f), 65535.f);
  return (unsigned short)x;
}

// ---------------------------------------------------------------------------
// Device body: 64x64 fp32->bf16 tile transpose (optional hi/lo split dst).
// smemf must hold 64*65 floats.
// ---------------------------------------------------------------------------
__device__ __forceinline__ void transpose_body(
    const float* __restrict__ src, unsigned short* __restrict__ dst,
    unsigned short* __restrict__ dstl, int srows, size_t r0, size_t c0,
    int t, float* smemf)
{
#pragma unroll
  for (int j = 0; j < 4; ++j) {
    int idx = j * 256 + t;
    int r = idx >> 4, c4 = (idx & 15) * 4;
    float4v v = *(const float4v*)&src[(r0 + (size_t)r) * 256 + c0 + c4];
    smemf[r * 65 + c4 + 0] = v[0]; smemf[r * 65 + c4 + 1] = v[1];
    smemf[r * 65 + c4 + 2] = v[2]; smemf[r * 65 + c4 + 3] = v[3];
  }
  __syncthreads();
#pragma unroll
  for (int j = 0; j < 4; ++j) {
    int idx = j * 256 + t;
    int dr = idx >> 4, p4 = (idx & 15) * 4;
    size_t o = (c0 + (size_t)dr) * (size_t)srows + r0 + p4;
    if (!dstl) {
      us4 oh;
#pragma unroll
      for (int e = 0; e < 4; ++e) oh[e] = f2bf(smemf[(p4 + e) * 65 + dr]);
      *(us4*)&dst[o] = oh;
    } else {
      us4 oh, ol;
#pragma unroll
      for (int e = 0; e < 4; ++e) {
        unsigned short h, l; split2(smemf[(p4 + e) * 65 + dr], h, l);
        oh[e] = h; ol[e] = l;
      }
      *(us4*)&dst[o] = oh;
      *(us4*)&dstl[o] = ol;
    }
  }
}

// ---------------------------------------------------------------------------
// Device body: U = relu(X[64rows,512] @ W[512,256]) (*D), hi/lo bf16 out.
// Pipelined: k0+1 global loads issued under the 48-MFMA window.
// smem must hold 51200 bytes.
// ---------------------------------------------------------------------------
template<int APPLY_D>
__device__ __forceinline__ void ugemm_body(
    const float* __restrict__ X,
    const unsigned short* __restrict__ Wth, const unsigned short* __restrict__ Wtl,
    const float* __restrict__ Dv,
    unsigned short* __restrict__ Uh, unsigned short* __restrict__ Ul,
    size_t m0, int t, unsigned char* smem)
{
  unsigned short* lAh = (unsigned short*)smem;             // [64][40]
  unsigned short* lAl = (unsigned short*)(smem + 5120);    // [64][40]
  unsigned short* lBh = (unsigned short*)(smem + 10240);   // [256][40]
  unsigned short* lBl = (unsigned short*)(smem + 30720);   // [256][40]
  const int w = t >> 6, l = t & 63;
  const int l15 = l & 15, lg = l >> 4, kr = lg * 8;
  const int arow = t >> 2, ac = (t & 3) * 8;
  const float* asrc = X + (m0 + arow) * 512 + ac;

  f32x4 acc[4][4] = {};
  float4v va0, va1;
  short8v vbh[4], vbl[4];

  va0 = *(const float4v*)(asrc);
  va1 = *(const float4v*)(asrc + 4);
#pragma unroll
  for (int j = 0; j < 4; ++j) {
    int idx = j * 256 + t;
    int row = idx >> 2, c = (idx & 3) * 8;
    size_t g = (size_t)row * 512 + c;
    vbh[j] = *(const short8v*)&Wth[g];
    vbl[j] = *(const short8v*)&Wtl[g];
  }

  for (int k0 = 0; k0 < 512; k0 += 32) {
    short8v ph, pl;
#pragma unroll
    for (int e = 0; e < 4; ++e) {
      unsigned short h, lo;
      split2(va0[e], h, lo); ph[e] = (short)h; pl[e] = (short)lo;
      split2(va1[e], h, lo); ph[4 + e] = (short)h; pl[4 + e] = (short)lo;
    }
    __syncthreads();
    *(short8v*)&lAh[arow * 40 + ac] = ph;
    *(short8v*)&lAl[arow * 40 + ac] = pl;
#pragma unroll
    for (int j = 0; j < 4; ++j) {
      int idx = j * 256 + t;
      int row = idx >> 2, c = (idx & 3) * 8;
      *(short8v*)&lBh[row * 40 + c] = vbh[j];
      *(short8v*)&lBl[row * 40 + c] = vbl[j];
    }
    __syncthreads();
    if (k0 < 480) {
      va0 = *(const float4v*)(asrc + k0 + 32);
      va1 = *(const float4v*)(asrc + k0 + 36);
#pragma unroll
      for (int j = 0; j < 4; ++j) {
        int idx = j * 256 + t;
        int row = idx >> 2, c = (idx & 3) * 8;
        size_t g = (size_t)row * 512 + k0 + 32 + c;
        vbh[j] = *(const short8v*)&Wth[g];
        vbl[j] = *(const short8v*)&Wtl[g];
      }
    }
    short8v ah[4], al[4];
#pragma unroll
    for (int mi = 0; mi < 4; ++mi) {
      ah[mi] = *(const short8v*)&lAh[(mi * 16 + l15) * 40 + kr];
      al[mi] = *(const short8v*)&lAl[(mi * 16 + l15) * 40 + kr];
    }
#pragma unroll
    for (int ni = 0; ni < 4; ++ni) {
      int rr = (w * 64 + ni * 16 + l15) * 40 + kr;
      short8v bh = *(const short8v*)&lBh[rr];
      short8v bl = *(const short8v*)&lBl[rr];
#pragma unroll
      for (int mi = 0; mi < 4; ++mi) {
        acc[mi][ni] = MFMA16(ah[mi], bh, acc[mi][ni]);
        acc[mi][ni] = MFMA16(ah[mi], bl, acc[mi][ni]);
        acc[mi][ni] = MFMA16(al[mi], bh, acc[mi][ni]);
      }
    }
  }
#pragma unroll
  for (int mi = 0; mi < 4; ++mi)
#pragma unroll
    for (int ni = 0; ni < 4; ++ni)
#pragma unroll
      for (int r = 0; r < 4; ++r) {
        size_t row = m0 + mi * 16 + lg * 4 + r;
        int col = w * 64 + ni * 16 + l15;
        float v = acc[mi][ni][r];
        v = v > 0.f ? v : 0.f;
        if (APPLY_D) v *= Dv[col];
        unsigned short h, lo; split2(v, h, lo);
        Uh[row * 256 + col] = h;
        Ul[row * 256 + col] = lo;
      }
}

// ---------------------------------------------------------------------------
// Kernel: W transpose only (32 blocks) - the only ugemm dependency.
// ---------------------------------------------------------------------------
__global__ __launch_bounds__(256) void transpose_w(
    const float* __restrict__ W,
    unsigned short* __restrict__ Wth, unsigned short* __restrict__ Wtl)
{
  __shared__ float lTf[64 * 65];
  const int blk = blockIdx.x;
  transpose_body(W, Wth, Wtl, 512, (size_t)(blk >> 2) * 64,
                 (size_t)(blk & 3) * 64, threadIdx.x, lTf);
}

// ---------------------------------------------------------------------------
// Kernel: prep_mega - one launch packing independent work:
//   blocks [0,1024):      ugemm<0> (passage -> Up)
//   blocks [1024,1152):   ugemm<1> (question -> Uq)
//   blocks [1152,5248):   rep_p transpose -> repTp
//   blocks [5248,5760):   rep transpose -> repT
// ---------------------------------------------------------------------------
__global__ __launch_bounds__(256) void prep_mega(
    const float* __restrict__ passage, const float* __restrict__ question,
    const float* __restrict__ rep, const float* __restrict__ rep_p,
    const unsigned short* __restrict__ Wth, const unsigned short* __restrict__ Wtl,
    const float* __restrict__ Dv,
    unsigned short* __restrict__ Uph, unsigned short* __restrict__ Upl,
    unsigned short* __restrict__ Uqh, unsigned short* __restrict__ Uql,
    unsigned short* __restrict__ repT, unsigned short* __restrict__ repTp)
{
  __shared__ __align__(16) unsigned char smem[51200];
  const int blk = blockIdx.x;
  const int t = threadIdx.x;
  if (blk < 1024) {
    ugemm_body<0>(passage, Wth, Wtl, nullptr, Uph, Upl,
                  (size_t)blk * 64, t, smem);
  } else if (blk < 1152) {
    ugemm_body<1>(question, Wth, Wtl, Dv, Uqh, Uql,
                  (size_t)(blk - 1024) * 64, t, smem);
  } else if (blk < 5248) {
    int rel = blk - 1152;
    int b = rel >> 8, tb = rel & 255;
    transpose_body(rep_p + (size_t)b * 4096 * 256,
                   repTp + (size_t)b * 256 * 4096, nullptr, 4096,
                   (size_t)(tb >> 2) * 64, (size_t)(tb & 3) * 64, t,
                   (float*)smem);
  } else {
    int rel = blk - 5248;
    int b = rel >> 5, tb = rel & 31;
    transpose_body(rep + (size_t)b * 512 * 256,
                   repT + (size_t)b * 256 * 512, nullptr, 512,
                   (size_t)(tb >> 2) * 64, (size_t)(tb & 3) * 64, t,
                   (float*)smem);
  }
}

// ---------------------------------------------------------------------------
// FALLBACK prep kernels (small ws path).
// ---------------------------------------------------------------------------
__global__ __launch_bounds__(256) void transpose_all(
    const float* __restrict__ W, const float* __restrict__ rep,
    const float* __restrict__ rep_p,
    unsigned short* __restrict__ Wth, unsigned short* __restrict__ Wtl,
    unsigned short* __restrict__ repT, unsigned short* __restrict__ repTp)
{
  __shared__ float lTf[64 * 65];
  const int blk = blockIdx.x;
  const int t = threadIdx.x;
  if (blk < 4096) {
    int b = blk >> 8, tb = blk & 255;
    transpose_body(rep_p + (size_t)b * 4096 * 256,
                   repTp + (size_t)b * 256 * 4096, nullptr, 4096,
                   (size_t)(tb >> 2) * 64, (size_t)(tb & 3) * 64, t, lTf);
  } else if (blk < 4608) {
    int rel = blk - 4096; int b = rel >> 5, tb = rel & 31;
    transpose_body(rep + (size_t)b * 512 * 256,
                   repT + (size_t)b * 256 * 512, nullptr, 512,
                   (size_t)(tb >> 2) * 64, (size_t)(tb & 3) * 64, t, lTf);
  } else {
    int rel = blk - 4608;
    transpose_body(W, Wth, Wtl, 512, (size_t)(rel >> 2) * 64,
                   (size_t)(rel & 3) * 64, t, lTf);
  }
}

template<int APPLY_D>
__global__ __launch_bounds__(256) void ugemm_kernel(
    const float* __restrict__ X,
    const unsigned short* __restrict__ Wth, const unsigned short* __restrict__ Wtl,
    const float* __restrict__ Dv,
    unsigned short* __restrict__ Uh, unsigned short* __restrict__ Ul)
{
  __shared__ __align__(16) unsigned char smem[51200];
  ugemm_body<APPLY_D>(X, Wth, Wtl, Dv, Uh, Ul,
                      (size_t)blockIdx.x * 64, threadIdx.x, smem);
}

// ---------------------------------------------------------------------------
// Kernel 2 (dir 2): softmax over Q then @ rep.
// 1024 threads / 16 waves (wr in [0,4) p-subtile, wc in [0,4) q-group),
// 128-row P-tile -> 2 blocks/CU = 32 waves/CU. Phase-1: B (Uq) staged in
// 128-q x 32-k chunks by threads t<512, DOUBLE-BUFFERED, 1 barrier/iter;
// A (Up) frags in regs from L2 (k0 prefetch). Each staged chunk feeds 2x
// the MFMA of the 512-thread version. Phase 2: two 64-row passes through
// probs[64][520]; per wave 1 rT frag -> 4 MFMA per k0 (acc2[4]).
// qcol(j) = (j>>1)*128 + wc*32 + (j&1)*16 + l15.
// If STORE_S: store p-masked S^T u16 (vs 32-row-subtile col max) + colmaxP.
// ---------------------------------------------------------------------------
template<int STORE_S>
__global__ __launch_bounds__(1024, 4) void dir2_kernel(
    const unsigned short* __restrict__ Uph, const unsigned short* __restrict__ Upl,
    const unsigned short* __restrict__ Uqh, const unsigned short* __restrict__ Uql,
    const unsigned short* __restrict__ repT, const unsigned char* __restrict__ qmask,
    const unsigned char* __restrict__ pmask, unsigned short* __restrict__ St,
    float* __restrict__ colmaxP, float* __restrict__ out)
{
  __shared__ __align__(16) unsigned char smem[70656];
  // phase 1: B dbuf [0,40960): buf k -> h at k*20480, l at +10240 ([128][40])
  // phase 2: probs [64][520] overlays [0,66560)
  unsigned short* probs = (unsigned short*)smem;
  float* smax = (float*)(smem + 66560);                        // [4][128]
  float* ssum = (float*)(smem + 68608);                        // [4][128]

  const int id = blockIdx.x;                     // 512 = 16b x 32 ptiles
  const int xcd = id & 7, r0b = id >> 3;         // r0b in [0,64)
  const int b = xcd * 2 + (r0b >> 5);            // 2 batches per XCD
  const int p0 = (r0b & 31) * 128;
  const int t = threadIdx.x;
  const int w = t >> 6, l = t & 63;
  const int wr = w >> 2, wc = w & 3;             // p-subtile / q-group
  const int l15 = l & 15, lg = l >> 4, kr = lg * 8;
  const int srow = (t >> 2) & 127, sc = (t & 3) * 8;  // B staging (t<512)

  const unsigned short* UqBh = Uqh + (size_t)b * 512 * 256;
  const unsigned short* UqBl = Uql + (size_t)b * 512 * 256;
  const size_t aoff = ((size_t)b * 4096 + p0 + wr * 32 + l15) * 256 + kr;
  const unsigned short* pAh0 = Uph + aoff;
  const unsigned short* pAh1 = pAh0 + 16 * 256;
  const unsigned short* pAl0 = Upl + aoff;
  const unsigned short* pAl1 = pAl0 + 16 * 256;

  auto lbh = [&](int buf) { return (unsigned short*)(smem + buf * 20480); };
  auto lbl = [&](int buf) { return (unsigned short*)(smem + buf * 20480 + 10240); };

  f32x4 acc[2][8] = {};
  short8v cah0, cah1, cal0, cal1;
  short8v nah0, nah1, nal0, nal1;
  short8v rh, rl;

  cah0 = *(const short8v*)&pAh0[0];
  cah1 = *(const short8v*)&pAh1[0];
  cal0 = *(const short8v*)&pAl0[0];
  cal1 = *(const short8v*)&pAl1[0];
  if (t < 512) {
    size_t g = (size_t)srow * 256 + sc;
    rh = *(const short8v*)&UqBh[g];
    rl = *(const short8v*)&UqBl[g];
    *(short8v*)&lbh(0)[srow * 40 + sc] = rh;
    *(short8v*)&lbl(0)[srow * 40 + sc] = rl;
  }
  __syncthreads();

  // ---- phase 1: S = Up_tile[128] @ Uq^T; 8 k0 x 4 q-halves, 1 barrier/iter
  for (int k0 = 0; k0 < 8; ++k0) {
#pragma unroll
    for (int qh = 0; qh < 4; ++qh) {
      const int cur = qh & 1;
      const bool last = (k0 == 7) && (qh == 3);
      if (!last && t < 512) {          // issue next-B loads
        int nk0 = (qh == 3) ? k0 + 1 : k0;
        int nqh = (qh == 3) ? 0 : qh + 1;
        size_t g = (size_t)(nqh * 128 + srow) * 256 + nk0 * 32 + sc;
        rh = *(const short8v*)&UqBh[g];
        rl = *(const short8v*)&UqBl[g];
      }
      if (qh == 3 && k0 < 7) {         // prefetch next-A frags
        size_t ao = (size_t)(k0 + 1) * 32;
        nah0 = *(const short8v*)&pAh0[ao];
        nah1 = *(const short8v*)&pAh1[ao];
        nal0 = *(const short8v*)&pAl0[ao];
        nal1 = *(const short8v*)&pAl1[ao];
      }
      const unsigned short* bhp = lbh(cur);
      const unsigned short* blp = lbl(cur);
#pragma unroll
      for (int qi = 0; qi < 2; ++qi) {
        int rr = (wc * 32 + qi * 16 + l15) * 40 + kr;
        short8v bh = *(const short8v*)&bhp[rr];
        short8v bl = *(const short8v*)&blp[rr];
        int j = qh * 2 + qi;
        acc[0][j] = MFMA16(cah0, bh, acc[0][j]);
        acc[0][j] = MFMA16(cah0, bl, acc[0][j]);
        acc[0][j] = MFMA16(cal0, bh, acc[0][j]);
        acc[1][j] = MFMA16(cah1, bh, acc[1][j]);
        acc[1][j] = MFMA16(cah1, bl, acc[1][j]);
        acc[1][j] = MFMA16(cal1, bh, acc[1][j]);
      }
      if (!last && t < 512) {          // write next-B to other buffer
        *(short8v*)&lbh(cur ^ 1)[srow * 40 + sc] = rh;
        *(short8v*)&lbl(cur ^ 1)[srow * 40 + sc] = rl;
      }
      if (qh == 3 && k0 < 7) { cah0 = nah0; cah1 = nah1; cal0 = nal0; cal1 = nal1; }
      __syncthreads();
    }
  }
  // acc[mi][j]: p-row = p0 + wr*32 + mi*16 + lg*4 + r
  // ---- optional: store p-masked S^T (u16 vs 32-row-subtile col max)
  if (STORE_S) {
    const unsigned char* pmk = pmask + (size_t)b * 4096 + p0 + wr * 32;
    unsigned int pmw0 = *(const unsigned int*)&pmk[lg * 4];
    unsigned int pmw1 = *(const unsigned int*)&pmk[16 + lg * 4];
#pragma unroll
    for (int j = 0; j < 8; ++j) {
      int qcol = ((j >> 1) << 7) + wc * 32 + ((j & 1) << 4) + l15;
      float a0[4], a1[4];
      float cm = -1e30f;
#pragma unroll
      for (int r = 0; r < 4; ++r) {
        a0[r] = ((pmw0 >> (8 * r)) & 0xFFu) ? -1e30f : acc[0][j][r];
        a1[r] = ((pmw1 >> (8 * r)) & 0xFFu) ? -1e30f : acc[1][j][r];
        cm = fmaxf(cm, fmaxf(a0[r], a1[r]));
      }
      cm = fmaxf(cm, __shfl_xor(cm, 16));
      cm = fmaxf(cm, __shfl_xor(cm, 32));
      us4 e0, e1;
#pragma unroll
      for (int r = 0; r < 4; ++r) {
        e0[r] = enc16(a0[r], cm);
        e1[r] = enc16(a1[r], cm);
      }
      size_t sb = ((size_t)b * 512 + qcol) * 4096 + p0 + wr * 32 + lg * 4;
      *(us4*)&St[sb]      = e0;
      *(us4*)&St[sb + 16] = e1;
      if (l < 16)
        colmaxP[((size_t)b * 128 + (p0 >> 5) + wr) * 512 + qcol] = cm;
    }
  }
  // ---- mask + softmax over q
  const unsigned char* qm = qmask + (size_t)b * 512;
#pragma unroll
  for (int j = 0; j < 8; ++j) {
    int qcol = ((j >> 1) << 7) + wc * 32 + ((j & 1) << 4) + l15;
    if (qm[qcol]) {
#pragma unroll
      for (int mi = 0; mi < 2; ++mi)
#pragma unroll
        for (int r = 0; r < 4; ++r) acc[mi][j][r] = -1e30f;
    }
  }
#pragma unroll
  for (int mi = 0; mi < 2; ++mi)
#pragma unroll
    for (int r = 0; r < 4; ++r) {
      float v = acc[mi][0][r];
#pragma unroll
      for (int j = 1; j < 8; ++j) v = fmaxf(v, acc[mi][j][r]);
      v = fmaxf(v, __shfl_xor(v, 1)); v = fmaxf(v, __shfl_xor(v, 2));
      v = fmaxf(v, __shfl_xor(v, 4)); v = fmaxf(v, __shfl_xor(v, 8));
      if (l15 == 0) smax[wc * 128 + wr * 32 + mi * 16 + lg * 4 + r] = v;
    }
  __syncthreads();          // B1: smax ready; fences phase-1 LDS reads
  float Mx[2][4];
#pragma unroll
  for (int mi = 0; mi < 2; ++mi)
#pragma unroll
    for (int r = 0; r < 4; ++r) {
      int row = wr * 32 + mi * 16 + lg * 4 + r;
      Mx[mi][r] = fmaxf(fmaxf(smax[row], smax[128 + row]),
                        fmaxf(smax[256 + row], smax[384 + row]));
    }
  float rs[2][4] = {};
#pragma unroll
  for (int mi = 0; mi < 2; ++mi)
#pragma unroll
    for (int j = 0; j < 8; ++j)
#pragma unroll
      for (int r = 0; r < 4; ++r) {
        float ev = __expf(acc[mi][j][r] - Mx[mi][r]);
        acc[mi][j][r] = ev;
        rs[mi][r] += ev;
      }
#pragma unroll
  for (int mi = 0; mi < 2; ++mi)
#pragma unroll
    for (int r = 0; r < 4; ++r) {
      float v = rs[mi][r];
      v += __shfl_xor(v, 1); v += __shfl_xor(v, 2);
      v += __shfl_xor(v, 4); v += __shfl_xor(v, 8);
      if (l15 == 0) ssum[wc * 128 + wr * 32 + mi * 16 + lg * 4 + r] = v;
    }
  // ---- phase 2: two 64-row passes (probs overlays B dbuf region)
  const unsigned short* rT = repT + (size_t)b * 131072;
  const unsigned short* rTb = rT + (size_t)(w * 16 + l15) * 512 + kr;
#pragma unroll
  for (int h = 0; h < 2; ++h) {
    __syncthreads();        // h=0: ssum ready; h=1: fences pass-0 probs reads
    if ((wr >> 1) == h) {   // waves owning rows [h*64, h*64+64) write probs
      const int lr0 = (wr & 1) * 32;
#pragma unroll
      for (int mi = 0; mi < 2; ++mi)
#pragma unroll
        for (int j = 0; j < 8; ++j) {
          int qcol = ((j >> 1) << 7) + wc * 32 + ((j & 1) << 4) + l15;
#pragma unroll
          for (int r = 0; r < 4; ++r)
            probs[(lr0 + mi * 16 + lg * 4 + r) * 520 + qcol] = f2bf(acc[mi][j][r]);
        }
    }
    __syncthreads();        // probs(half h) ready
    float invv[4][4];
#pragma unroll
    for (int mi = 0; mi < 4; ++mi)
#pragma unroll
      for (int r = 0; r < 4; ++r) {
        int row = h * 64 + mi * 16 + lg * 4 + r;
        invv[mi][r] = 1.0f / (ssum[row] + ssum[128 + row] +
                              ssum[256 + row] + ssum[384 + row]);
      }
    f32x4 acc2[4] = {};
    short8v cb = *(const short8v*)(rTb);
    for (int k0 = 0; k0 < 512; k0 += 32) {
      int kn = (k0 + 32) & 511;        // k+1 prefetch (wraps harmlessly)
      short8v nb = *(const short8v*)(rTb + kn);
      short8v a0 = *(const short8v*)&probs[(l15) * 520 + k0 + kr];
      short8v a1 = *(const short8v*)&probs[(16 + l15) * 520 + k0 + kr];
      short8v a2 = *(const short8v*)&probs[(32 + l15) * 520 + k0 + kr];
      short8v a3 = *(const short8v*)&probs[(48 + l15) * 520 + k0 + kr];
      acc2[0] = MFMA16(a0, cb, acc2[0]);
      acc2[1] = MFMA16(a1, cb, acc2[1]);
      acc2[2] = MFMA16(a2, cb, acc2[2]);
      acc2[3] = MFMA16(a3, cb, acc2[3]);
      cb = nb;
    }
#pragma unroll
    for (int mi = 0; mi < 4; ++mi)
#pragma unroll
      for (int r = 0; r < 4; ++r) {
        int row = p0 + h * 64 + mi * 16 + lg * 4 + r;
        int col = w * 16 + l15;
        out[((size_t)b * 4096 + row) * 256 + col] = acc2[mi][r] * invv[mi][r];
      }
  }
}

// ---------------------------------------------------------------------------
// Kernel (dir 1): O_q partial = exp(S^T - M) @ rep_p over a 1024-p chunk.
// Grid 1024 = 16b x 16qt x 4chunk. Pipelined (V dbuf in regs, St 1 tile
// early). ONE barrier per tile.
// ---------------------------------------------------------------------------
__global__ __launch_bounds__(256) void dir1_pv(
    const unsigned short* __restrict__ St, const float* __restrict__ colmaxP,
    const unsigned short* __restrict__ repTp,
    float* __restrict__ accP, float* __restrict__ mlP)
{
  __shared__ unsigned short lAe[2][32 * 72];
  const int id = blockIdx.x;
  const int xcd = id & 7, r0 = id >> 3;
  const int b = xcd * 2 + (r0 >> 6);
  const int rem = r0 & 63;
  const int qt = rem >> 2, ch = rem & 3;
  const int q0 = qt * 32, pbeg = ch * 1024;
  const int pi = (b * 16 + qt) * 4 + ch;
  const int NT = 16;

  const int t = threadIdx.x;
  const int w = t >> 6, l = t & 63;
  const int l15 = l & 15, lg = l >> 4, kr = lg * 8;
  const int srow = t >> 3, sp = (t & 7) * 8;

  const float* cmq = colmaxP + (size_t)b * 128 * 512 + q0 + srow;
  float mq_s;
  {
    const int part = t & 7;
    float m = -1e30f;
#pragma unroll
    for (int j = 0; j < 16; ++j)
      m = fmaxf(m, cmq[(size_t)(part + j * 8) * 512]);
    m = fmaxf(m, __shfl_xor(m, 1));
    m = fmaxf(m, __shfl_xor(m, 2));
    m = fmaxf(m, __shfl_xor(m, 4));
    mq_s = m;
  }
  const unsigned short* Sb = St + ((size_t)b * 512 + q0 + srow) * 4096;
  const unsigned short* vtb = repTp + ((size_t)b * 256 + w * 64 + l15) * 4096;
  float rsum = 0.f;
  f32x4 acc[2][4] = {};
  us8v u; float cmv;
  short8v bvA[2][4], bvB[2][4];

  auto STAGE_LOAD = [&](int tile) {
    int pelem = pbeg + tile * 64 + sp;
    u = *(const us8v*)(Sb + pelem);
    cmv = cmq[(size_t)(pelem >> 5) * 512];
  };
  auto STAGE_FINISH = [&](int buf) {
    float base = cmv - 20.f - mq_s;
    short8v pk;
#pragma unroll
    for (int e = 0; e < 8; ++e) {
      float ev = __expf((float)u[e] * (1.f / 3276.8f) + base);
      rsum += ev;
      pk[e] = (short)f2bf(ev);
    }
    *(short8v*)&lAe[buf][srow * 72 + sp] = pk;
  };
  auto BV_LOAD = [&](int tile, short8v (&bv)[2][4]) {
    int p0v = pbeg + tile * 64;
#pragma unroll
    for (int ks = 0; ks < 2; ++ks)
#pragma unroll
      for (int di = 0; di < 4; ++di)
        bv[ks][di] = *(const short8v*)&vtb[(size_t)(di * 16) * 4096 + p0v + ks * 32 + kr];
  };
  auto COMPUTE = [&](int buf, short8v (&bv)[2][4]) {
#pragma unroll
    for (int ks = 0; ks < 2; ++ks) {
      short8v pa0 = *(const short8v*)&lAe[buf][l15 * 72 + ks * 32 + kr];
      short8v pa1 = *(const short8v*)&lAe[buf][(16 + l15) * 72 + ks * 32 + kr];
#pragma unroll
      for (int di = 0; di < 4; ++di) {
        acc[0][di] = MFMA16(pa0, bv[ks][di], acc[0][di]);
        acc[1][di] = MFMA16(pa1, bv[ks][di], acc[1][di]);
      }
    }
  };

  STAGE_LOAD(0);
  BV_LOAD(0, bvA);
  STAGE_FINISH(0);
  STAGE_LOAD(1);
  __syncthreads();

#pragma unroll 1
  for (int tt = 0; tt < NT; tt += 2) {
    const bool has1 = (tt + 1 < NT), has2 = (tt + 2 < NT), has3 = (tt + 3 < NT);
    if (has1) BV_LOAD(tt + 1, bvB);
    COMPUTE(0, bvA);
    if (has1) STAGE_FINISH(1);
    if (has2) STAGE_LOAD(tt + 2);
    __syncthreads();
    if (has1) {
      if (has2) BV_LOAD(tt + 2, bvA);
      COMPUTE(1, bvB);
      if (has2) STAGE_FINISH(0);
      if (has3) STAGE_LOAD(tt + 3);
      __syncthreads();
    }
  }

  rsum += __shfl_xor(rsum, 1);
  rsum += __shfl_xor(rsum, 2);
  rsum += __shfl_xor(rsum, 4);
  if ((t & 7) == 0) mlP[(size_t)pi * 32 + srow] = rsum;

  float* ab = accP + (size_t)pi * 32 * 256;
#pragma unroll
  for (int mi = 0; mi < 2; ++mi)
#pragma unroll
    for (int di = 0; di < 4; ++di)
#pragma unroll
      for (int r = 0; r < 4; ++r) {
        int row = mi * 16 + lg * 4 + r;
        int col = w * 64 + di * 16 + l15;
        ab[(size_t)row * 256 + col] = acc[mi][di][r];
      }
}

// ---------------------------------------------------------------------------
// Kernel: merge 4 sum-partials (shared true max -> plain sums) -> outq.
// ---------------------------------------------------------------------------
__global__ __launch_bounds__(256) void merge4_kernel(
    const float* __restrict__ accP, const float* __restrict__ mlP,
    float* __restrict__ outq)
{
  const int g = blockIdx.x * 256 + threadIdx.x;
  const int row = g >> 6;
  const int d0 = (g & 63) * 4;
  const int b = row >> 9, q = row & 511;
  const int qt = q >> 5, ri = q & 31;
  const int pbase = (b * 16 + qt) * 4;
  float s = 0.f;
  float4v o = {0.f, 0.f, 0.f, 0.f};
#pragma unroll
  for (int c = 0; c < 4; ++c) {
    s += mlP[(size_t)(pbase + c) * 32 + ri];
    float4v a = *(const float4v*)&accP[((size_t)(pbase + c) * 32 + ri) * 256 + d0];
#pragma unroll
    for (int k = 0; k < 4; ++k) o[k] += a[k];
  }
  float inv = 1.0f / s;
#pragma unroll
  for (int k = 0; k < 4; ++k) o[k] *= inv;
  *(float4v*)&outq[(size_t)row * 256 + d0] = o;
}

// ---------------------------------------------------------------------------
// FALLBACK (small ws): round-3 split-K flash dir1 + LSE merge + simple dir2.
// ---------------------------------------------------------------------------
__global__ __launch_bounds__(256) void dir1_partial(
    const unsigned short* __restrict__ Uph, const unsigned short* __restrict__ Upl,
    const unsigned short* __restrict__ Uqh, const unsigned short* __restrict__ Uql,
    const unsigned short* __restrict__ repTp, const unsigned char* __restrict__ pmask,
    float* __restrict__ accP, float* __restrict__ mlP)
{
  __shared__ __align__(16) unsigned char smem[39424];
  unsigned short* lAh = (unsigned short*)smem;
  unsigned short* lAl = (unsigned short*)(smem + 16896);
  unsigned short* lP  = (unsigned short*)(smem + 33792);
  float* smax = (float*)(smem + 38400);
  float* ssum = (float*)(smem + 38912);

  const int id  = blockIdx.x;
  const int xcd = id & 7, rr0 = id >> 3;
  const int b   = xcd * 2 + (rr0 >> 6);
  const int rem = rr0 & 63;
  const int qt  = rem >> 2, ch = rem & 3;
  const int q0  = qt * 32;
  const int pbeg = ch * 1024;
  const int pi  = (b * 16 + qt) * 4 + ch;

  const int t = threadIdx.x;
  const int w = t >> 6, l = t & 63;
  const int l15 = l & 15, lg = l >> 4, kr = lg * 8;

#pragma unroll
  for (int j = 0; j < 4; ++j) {
    int idx = j * 256 + t;
    int row = idx >> 5, c = (idx & 31) * 8;
    size_t g = ((size_t)b * 512 + q0 + row) * 256 + c;
    *(short8v*)&lAh[row * 264 + c] = *(const short8v*)&Uqh[g];
    *(short8v*)&lAl[row * 264 + c] = *(const short8v*)&Uql[g];
  }
  float m_r[2][4], l_r[2][4];
#pragma unroll
  for (int mi = 0; mi < 2; ++mi)
#pragma unroll
    for (int r = 0; r < 4; ++r) { m_r[mi][r] = -1e30f; l_r[mi][r] = 0.f; }
  f32x4 accO[2][4] = {};
  const size_t upoff = ((size_t)b * 4096 + w * 16 + l15) * 256;
  const unsigned short* upbh = Uph + upoff;
  const unsigned short* upbl = Upl + upoff;
  const unsigned short* vtb = repTp + (size_t)b * 1048576;
  const unsigned char* pm = pmask + (size_t)b * 4096;
  __syncthreads();

  for (int p0 = pbeg; p0 < pbeg + 1024; p0 += 64) {
    f32x4 s[2] = {};
#pragma unroll
    for (int k0 = 0; k0 < 256; k0 += 32) {
      short8v ah0 = *(const short8v*)&lAh[l15 * 264 + k0 + kr];
      short8v ah1 = *(const short8v*)&lAh[(16 + l15) * 264 + k0 + kr];
      short8v al0 = *(const short8v*)&lAl[l15 * 264 + k0 + kr];
      short8v al1 = *(const short8v*)&lAl[(16 + l15) * 264 + k0 + kr];
      short8v bvh = *(const short8v*)&upbh[(size_t)p0 * 256 + k0 + kr];
      short8v bvl = *(const short8v*)&upbl[(size_t)p0 * 256 + k0 + kr];
      s[0] = MFMA16(ah0, bvh, s[0]);
      s[0] = MFMA16(ah0, bvl, s[0]);
      s[0] = MFMA16(al0, bvh, s[0]);
      s[1] = MFMA16(ah1, bvh, s[1]);
      s[1] = MFMA16(ah1, bvl, s[1]);
      s[1] = MFMA16(al1, bvh, s[1]);
    }
    if (pm[p0 + w * 16 + l15]) {
#pragma unroll
      for (int mi = 0; mi < 2; ++mi)
#pragma unroll
        for (int r = 0; r < 4; ++r) s[mi][r] = -1e30f;
    }
#pragma unroll
    for (int mi = 0; mi < 2; ++mi)
#pragma unroll
      for (int r = 0; r < 4; ++r) {
        float v = s[mi][r];
        v = fmaxf(v, __shfl_xor(v, 1)); v = fmaxf(v, __shfl_xor(v, 2));
        v = fmaxf(v, __shfl_xor(v, 4)); v = fmaxf(v, __shfl_xor(v, 8));
        if (l15 == 0) smax[w * 32 + mi * 16 + lg * 4 + r] = v;
      }
    __syncthreads();
    float mnew[2][4], fsc[2][4], e[2][4];
#pragma unroll
    for (int mi = 0; mi < 2; ++mi)
#pragma unroll
      for (int r = 0; r < 4; ++r) {
        int row = mi * 16 + lg * 4 + r;
        float tm = fmaxf(fmaxf(smax[row], smax[32 + row]),
                         fmaxf(smax[64 + row], smax[96 + row]));
        float mn = fmaxf(m_r[mi][r], tm);
        mnew[mi][r] = mn;
        fsc[mi][r] = __expf(m_r[mi][r] - mn);
        e[mi][r] = __expf(s[mi][r] - mn);
      }
#pragma unroll
    for (int mi = 0; mi < 2; ++mi)
#pragma unroll
      for (int r = 0; r < 4; ++r) {
        float v = e[mi][r];
        v += __shfl_xor(v, 1); v += __shfl_xor(v, 2);
        v += __shfl_xor(v, 4); v += __shfl_xor(v, 8);
        if (l15 == 0) ssum[w * 32 + mi * 16 + lg * 4 + r] = v;
        lP[(mi * 16 + lg * 4 + r) * 72 + w * 16 + l15] = f2bf(e[mi][r]);
      }
    __syncthreads();
#pragma unroll
    for (int mi = 0; mi < 2; ++mi)
#pragma unroll
      for (int r = 0; r < 4; ++r) {
        int row = mi * 16 + lg * 4 + r;
        float ts = ssum[row] + ssum[32 + row] + ssum[64 + row] + ssum[96 + row];
        l_r[mi][r] = l_r[mi][r] * fsc[mi][r] + ts;
        m_r[mi][r] = mnew[mi][r];
      }
#pragma unroll
    for (int mi = 0; mi < 2; ++mi)
#pragma unroll
      for (int di = 0; di < 4; ++di)
#pragma unroll
        for (int r = 0; r < 4; ++r) accO[mi][di][r] *= fsc[mi][r];
#pragma unroll
    for (int ks = 0; ks < 64; ks += 32) {
      short8v pa0 = *(const short8v*)&lP[l15 * 72 + ks + kr];
      short8v pa1 = *(const short8v*)&lP[(16 + l15) * 72 + ks + kr];
#pragma unroll
      for (int di = 0; di < 4; ++di) {
        short8v bv = *(const short8v*)&vtb[(size_t)(w * 64 + di * 16 + l15) * 4096 + p0 + ks + kr];
        accO[0][di] = MFMA16(pa0, bv, accO[0][di]);
        accO[1][di] = MFMA16(pa1, bv, accO[1][di]);
      }
    }
  }
  float* ab = accP + (size_t)pi * 32 * 256;
#pragma unroll
  for (int mi = 0; mi < 2; ++mi)
#pragma unroll
    for (int di = 0; di < 4; ++di)
#pragma unroll
      for (int r = 0; r < 4; ++r) {
        int row = mi * 16 + lg * 4 + r;
        int col = w * 64 + di * 16 + l15;
        ab[(size_t)row * 256 + col] = accO[mi][di][r];
      }
  if (w == 0 && l15 == 0) {
#pragma unroll
    for (int mi = 0; mi < 2; ++mi)
#pragma unroll
      for (int r = 0; r < 4; ++r) {
        int row = mi * 16 + lg * 4 + r;
        mlP[((size_t)pi * 32 + row) * 2 + 0] = m_r[mi][r];
        mlP[((size_t)pi * 32 + row) * 2 + 1] = l_r[mi][r];
      }
  }
}

__global__ __launch_bounds__(256) void merge_kernel(
    const float* __restrict__ accP, const float* __restrict__ mlP,
    float* __restrict__ outq)
{
  const int g = blockIdx.x * 256 + threadIdx.x;
  const int row = g >> 6;
  const int d0 = (g & 63) * 4;
  const int b = row >> 9, q = row & 511;
  const int qt = q >> 5, ri = q & 31;
  const int pbase = (b * 16 + qt) * 4;
  float m[4], lv[4];
  float M = -1e30f;
#pragma unroll
  for (int c = 0; c < 4; ++c) {
    m[c]  = mlP[((size_t)(pbase + c) * 32 + ri) * 2 + 0];
    lv[c] = mlP[((size_t)(pbase + c) * 32 + ri) * 2 + 1];
    M = fmaxf(M, m[c]);
  }
  float s = 0.f;
  float4v o = {0.f, 0.f, 0.f, 0.f};
#pragma unroll
  for (int c = 0; c < 4; ++c) {
    float e = __expf(m[c] - M);
    s += e * lv[c];
    float4v a = *(const float4v*)&accP[((size_t)(pbase + c) * 32 + ri) * 256 + d0];
#pragma unroll
    for (int k = 0; k < 4; ++k) o[k] += e * a[k];
  }
  float inv = 1.0f / s;
#pragma unroll
  for (int k = 0; k < 4; ++k) o[k] *= inv;
  *(float4v*)&outq[(size_t)row * 256 + d0] = o;
}

// ---------------------------------------------------------------------------
extern "C" void kernel_launch(void* const* d_in, const int* in_sizes, int n_in,
                              void* d_out, int out_size, void* d_ws, size_t ws_size,
                              hipStream_t stream) {
  (void)in_sizes; (void)n_in; (void)out_size;
  const float* passage        = (const float*)d_in[0];
  const unsigned char* p_mask = (const unsigned char*)d_in[1];
  const float* question       = (const float*)d_in[2];
  const unsigned char* q_mask = (const unsigned char*)d_in[3];
  const float* rep            = (const float*)d_in[4];
  const float* rep_p          = (const float*)d_in[5];
  const float* W              = (const float*)d_in[6];
  const float* Dv             = (const float*)d_in[7];

  unsigned short* Wth   = (unsigned short*)d_ws;           // [256][512]
  unsigned short* Wtl   = Wth   + 131072;
  unsigned short* repT  = Wtl   + 131072;                  // [16][256][512]
  unsigned short* repTp = repT  + 2097152;                 // [16][256][4096]
  unsigned short* Uqh   = repTp + 16777216;                // [16*512][256]
  unsigned short* Uql   = Uqh   + 2097152;
  unsigned short* Uph   = Uql   + 2097152;                 // [16*4096][256]
  unsigned short* Upl   = Uph   + 16777216;
  // big-ws extras (beyond the 108.5 MB above):
  unsigned short* StU = (unsigned short*)((char*)d_ws + 113770496ULL); // [16][512][4096] u16
  float* colmaxP      = (float*)((char*)d_ws + 180879360ULL);          // [16][128][512]
  const size_t NEEDED = 185073664ULL;

  float* out  = (float*)d_out;                             // [16,4096,256]
  float* outq = out + (size_t)16 * 4096 * 256;             // [16,512,256]

  if (ws_size >= NEEDED) {
    // S-once path; prep fused; dir2 = 1024-thread 128-row tiles.
    float* accP4 = (float*)Uph;          // 33.5 MB, Up dead after dir2
    float* mlP4  = (float*)Uqh;          // 128 KB, Uq dead after dir2
    transpose_w<<<32, 256, 0, stream>>>(W, Wth, Wtl);
    prep_mega<<<5760, 256, 0, stream>>>(passage, question, rep, rep_p,
                                        Wth, Wtl, Dv, Uph, Upl, Uqh, Uql,
                                        repT, repTp);
    dir2_kernel<1><<<512, 1024, 0, stream>>>(Uph, Upl, Uqh, Uql, repT,
                                             q_mask, p_mask, StU, colmaxP, out);
    dir1_pv<<<1024, 256, 0, stream>>>(StU, colmaxP, repTp, accP4, mlP4);
    merge4_kernel<<<2048, 256, 0, stream>>>(accP4, mlP4, outq);
  } else {
    // fallback: round-3 split-K flash (accP in out region, before dir2)
    float* accP = out;
    float* mlP  = (float*)Wth;
    transpose_all<<<4640, 256, 0, stream>>>(W, rep, rep_p, Wth, Wtl, repT, repTp);
    ugemm_kernel<0><<<1024, 256, 0, stream>>>(passage,  Wth, Wtl, nullptr, Uph, Upl);
    ugemm_kernel<1><<<128,  256, 0, stream>>>(question, Wth, Wtl, Dv,      Uqh, Uql);
    dir1_partial<<<1024, 256, 0, stream>>>(Uph, Upl, Uqh, Uql, repTp, p_mask, accP, mlP);
    merge_kernel<<<2048, 256, 0, stream>>>(accP, mlP, outq);
    dir2_kernel<0><<<512, 1024, 0, stream>>>(Uph, Upl, Uqh, Uql, repT,
                                             q_mask, nullptr, nullptr, nullptr, out);
  }
}

// Round 14
// 312.056 us; speedup vs baseline: 1.0178x; 1.0178x over previous
//
#include <hip/hip_runtime.h>

// ---------------------------------------------------------------------------
// FullAttention (bidirectional attention) on MI355X.
// B=16, P=4096, Q=512, D_IN=512, H=256, DR=256. Outputs fp32.
// Score path uses double-bf16 (hi+lo) splits: 3-pass MFMA per GEMM.
// prep_mega: ugemm<0> + ugemm<1> + rep/rep_p transposes IN ONE LAUNCH.
// dir2 (round-12 512-thread version - best measured; the 1024-thread
// 128-row variant REGRESSED to 142us, occupancy gain eaten by sync):
// 8-wave 64-row P-tile, 1-barrier dbuf B staging, A-frags from L2,
// fused phase 2 (probs[64][520], rT frags once per k0 feed 8 MFMAs).
// launch_bounds(512,4): DO NOT raise min-waves (round-8: spill, 4x slower).
// dir1 = exp(S^T-M) @ rep_p, split-4 over p, deep register prefetch (T14),
// s_setprio(1) around MFMA cluster (T5: wave role diversity here).
// ---------------------------------------------------------------------------

typedef float  f32x4   __attribute__((ext_vector_type(4)));
typedef float  float4v __attribute__((ext_vector_type(4)));
typedef short  short8v __attribute__((ext_vector_type(8)));
typedef unsigned short us4 __attribute__((ext_vector_type(4)));
typedef unsigned short us8v __attribute__((ext_vector_type(8)));

#define MFMA16(a,b,c) __builtin_amdgcn_mfma_f32_16x16x32_bf16((a),(b),(c),0,0,0)

__device__ __forceinline__ unsigned short f2bf(float f) {
  unsigned int u = __builtin_bit_cast(unsigned int, f);
  u += 0x7FFFu + ((u >> 16) & 1u);           // round-to-nearest-even
  return (unsigned short)(u >> 16);
}
__device__ __forceinline__ float bf2f(unsigned short h) {
  unsigned int u = (unsigned int)h << 16;
  return __builtin_bit_cast(float, u);
}
__device__ __forceinline__ void split2(float v, unsigned short& h, unsigned short& l) {
  h = f2bf(v);
  l = f2bf(v - bf2f(h));
}
__device__ __forceinline__ unsigned short enc16(float a, float cm) {
  float x = (a - cm + 20.f) * 3276.8f + 0.5f;
  x = fminf(fmaxf(x, 0.f), 65535.f);
  return (unsigned short)x;
}

// ---------------------------------------------------------------------------
// Device body: 64x64 fp32->bf16 tile transpose (optional hi/lo split dst).
// smemf must hold 64*65 floats.
// ---------------------------------------------------------------------------
__device__ __forceinline__ void transpose_body(
    const float* __restrict__ src, unsigned short* __restrict__ dst,
    unsigned short* __restrict__ dstl, int srows, size_t r0, size_t c0,
    int t, float* smemf)
{
#pragma unroll
  for (int j = 0; j < 4; ++j) {
    int idx = j * 256 + t;
    int r = idx >> 4, c4 = (idx & 15) * 4;
    float4v v = *(const float4v*)&src[(r0 + (size_t)r) * 256 + c0 + c4];
    smemf[r * 65 + c4 + 0] = v[0]; smemf[r * 65 + c4 + 1] = v[1];
    smemf[r * 65 + c4 + 2] = v[2]; smemf[r * 65 + c4 + 3] = v[3];
  }
  __syncthreads();
#pragma unroll
  for (int j = 0; j < 4; ++j) {
    int idx = j * 256 + t;
    int dr = idx >> 4, p4 = (idx & 15) * 4;
    size_t o = (c0 + (size_t)dr) * (size_t)srows + r0 + p4;
    if (!dstl) {
      us4 oh;
#pragma unroll
      for (int e = 0; e < 4; ++e) oh[e] = f2bf(smemf[(p4 + e) * 65 + dr]);
      *(us4*)&dst[o] = oh;
    } else {
      us4 oh, ol;
#pragma unroll
      for (int e = 0; e < 4; ++e) {
        unsigned short h, l; split2(smemf[(p4 + e) * 65 + dr], h, l);
        oh[e] = h; ol[e] = l;
      }
      *(us4*)&dst[o] = oh;
      *(us4*)&dstl[o] = ol;
    }
  }
}

// ---------------------------------------------------------------------------
// Device body: U = relu(X[64rows,512] @ W[512,256]) (*D), hi/lo bf16 out.
// Pipelined: k0+1 global loads issued under the 48-MFMA window.
// smem must hold 51200 bytes.
// ---------------------------------------------------------------------------
template<int APPLY_D>
__device__ __forceinline__ void ugemm_body(
    const float* __restrict__ X,
    const unsigned short* __restrict__ Wth, const unsigned short* __restrict__ Wtl,
    const float* __restrict__ Dv,
    unsigned short* __restrict__ Uh, unsigned short* __restrict__ Ul,
    size_t m0, int t, unsigned char* smem)
{
  unsigned short* lAh = (unsigned short*)smem;             // [64][40]
  unsigned short* lAl = (unsigned short*)(smem + 5120);    // [64][40]
  unsigned short* lBh = (unsigned short*)(smem + 10240);   // [256][40]
  unsigned short* lBl = (unsigned short*)(smem + 30720);   // [256][40]
  const int w = t >> 6, l = t & 63;
  const int l15 = l & 15, lg = l >> 4, kr = lg * 8;
  const int arow = t >> 2, ac = (t & 3) * 8;
  const float* asrc = X + (m0 + arow) * 512 + ac;

  f32x4 acc[4][4] = {};
  float4v va0, va1;
  short8v vbh[4], vbl[4];

  va0 = *(const float4v*)(asrc);
  va1 = *(const float4v*)(asrc + 4);
#pragma unroll
  for (int j = 0; j < 4; ++j) {
    int idx = j * 256 + t;
    int row = idx >> 2, c = (idx & 3) * 8;
    size_t g = (size_t)row * 512 + c;
    vbh[j] = *(const short8v*)&Wth[g];
    vbl[j] = *(const short8v*)&Wtl[g];
  }

  for (int k0 = 0; k0 < 512; k0 += 32) {
    short8v ph, pl;
#pragma unroll
    for (int e = 0; e < 4; ++e) {
      unsigned short h, lo;
      split2(va0[e], h, lo); ph[e] = (short)h; pl[e] = (short)lo;
      split2(va1[e], h, lo); ph[4 + e] = (short)h; pl[4 + e] = (short)lo;
    }
    __syncthreads();
    *(short8v*)&lAh[arow * 40 + ac] = ph;
    *(short8v*)&lAl[arow * 40 + ac] = pl;
#pragma unroll
    for (int j = 0; j < 4; ++j) {
      int idx = j * 256 + t;
      int row = idx >> 2, c = (idx & 3) * 8;
      *(short8v*)&lBh[row * 40 + c] = vbh[j];
      *(short8v*)&lBl[row * 40 + c] = vbl[j];
    }
    __syncthreads();
    if (k0 < 480) {
      va0 = *(const float4v*)(asrc + k0 + 32);
      va1 = *(const float4v*)(asrc + k0 + 36);
#pragma unroll
      for (int j = 0; j < 4; ++j) {
        int idx = j * 256 + t;
        int row = idx >> 2, c = (idx & 3) * 8;
        size_t g = (size_t)row * 512 + k0 + 32 + c;
        vbh[j] = *(const short8v*)&Wth[g];
        vbl[j] = *(const short8v*)&Wtl[g];
      }
    }
    short8v ah[4], al[4];
#pragma unroll
    for (int mi = 0; mi < 4; ++mi) {
      ah[mi] = *(const short8v*)&lAh[(mi * 16 + l15) * 40 + kr];
      al[mi] = *(const short8v*)&lAl[(mi * 16 + l15) * 40 + kr];
    }
#pragma unroll
    for (int ni = 0; ni < 4; ++ni) {
      int rr = (w * 64 + ni * 16 + l15) * 40 + kr;
      short8v bh = *(const short8v*)&lBh[rr];
      short8v bl = *(const short8v*)&lBl[rr];
#pragma unroll
      for (int mi = 0; mi < 4; ++mi) {
        acc[mi][ni] = MFMA16(ah[mi], bh, acc[mi][ni]);
        acc[mi][ni] = MFMA16(ah[mi], bl, acc[mi][ni]);
        acc[mi][ni] = MFMA16(al[mi], bh, acc[mi][ni]);
      }
    }
  }
#pragma unroll
  for (int mi = 0; mi < 4; ++mi)
#pragma unroll
    for (int ni = 0; ni < 4; ++ni)
#pragma unroll
      for (int r = 0; r < 4; ++r) {
        size_t row = m0 + mi * 16 + lg * 4 + r;
        int col = w * 64 + ni * 16 + l15;
        float v = acc[mi][ni][r];
        v = v > 0.f ? v : 0.f;
        if (APPLY_D) v *= Dv[col];
        unsigned short h, lo; split2(v, h, lo);
        Uh[row * 256 + col] = h;
        Ul[row * 256 + col] = lo;
      }
}

// ---------------------------------------------------------------------------
// Kernel: W transpose only (32 blocks) - the only ugemm dependency.
// ---------------------------------------------------------------------------
__global__ __launch_bounds__(256) void transpose_w(
    const float* __restrict__ W,
    unsigned short* __restrict__ Wth, unsigned short* __restrict__ Wtl)
{
  __shared__ float lTf[64 * 65];
  const int blk = blockIdx.x;
  transpose_body(W, Wth, Wtl, 512, (size_t)(blk >> 2) * 64,
                 (size_t)(blk & 3) * 64, threadIdx.x, lTf);
}

// ---------------------------------------------------------------------------
// Kernel: prep_mega - one launch packing independent work:
//   blocks [0,1024):      ugemm<0> (passage -> Up)
//   blocks [1024,1152):   ugemm<1> (question -> Uq)
//   blocks [1152,5248):   rep_p transpose -> repTp
//   blocks [5248,5760):   rep transpose -> repT
// ---------------------------------------------------------------------------
__global__ __launch_bounds__(256) void prep_mega(
    const float* __restrict__ passage, const float* __restrict__ question,
    const float* __restrict__ rep, const float* __restrict__ rep_p,
    const unsigned short* __restrict__ Wth, const unsigned short* __restrict__ Wtl,
    const float* __restrict__ Dv,
    unsigned short* __restrict__ Uph, unsigned short* __restrict__ Upl,
    unsigned short* __restrict__ Uqh, unsigned short* __restrict__ Uql,
    unsigned short* __restrict__ repT, unsigned short* __restrict__ repTp)
{
  __shared__ __align__(16) unsigned char smem[51200];
  const int blk = blockIdx.x;
  const int t = threadIdx.x;
  if (blk < 1024) {
    ugemm_body<0>(passage, Wth, Wtl, nullptr, Uph, Upl,
                  (size_t)blk * 64, t, smem);
  } else if (blk < 1152) {
    ugemm_body<1>(question, Wth, Wtl, Dv, Uqh, Uql,
                  (size_t)(blk - 1024) * 64, t, smem);
  } else if (blk < 5248) {
    int rel = blk - 1152;
    int b = rel >> 8, tb = rel & 255;
    transpose_body(rep_p + (size_t)b * 4096 * 256,
                   repTp + (size_t)b * 256 * 4096, nullptr, 4096,
                   (size_t)(tb >> 2) * 64, (size_t)(tb & 3) * 64, t,
                   (float*)smem);
  } else {
    int rel = blk - 5248;
    int b = rel >> 5, tb = rel & 31;
    transpose_body(rep + (size_t)b * 512 * 256,
                   repT + (size_t)b * 256 * 512, nullptr, 512,
                   (size_t)(tb >> 2) * 64, (size_t)(tb & 3) * 64, t,
                   (float*)smem);
  }
}

// ---------------------------------------------------------------------------
// FALLBACK prep kernels (small ws path).
// ---------------------------------------------------------------------------
__global__ __launch_bounds__(256) void transpose_all(
    const float* __restrict__ W, const float* __restrict__ rep,
    const float* __restrict__ rep_p,
    unsigned short* __restrict__ Wth, unsigned short* __restrict__ Wtl,
    unsigned short* __restrict__ repT, unsigned short* __restrict__ repTp)
{
  __shared__ float lTf[64 * 65];
  const int blk = blockIdx.x;
  const int t = threadIdx.x;
  if (blk < 4096) {
    int b = blk >> 8, tb = blk & 255;
    transpose_body(rep_p + (size_t)b * 4096 * 256,
                   repTp + (size_t)b * 256 * 4096, nullptr, 4096,
                   (size_t)(tb >> 2) * 64, (size_t)(tb & 3) * 64, t, lTf);
  } else if (blk < 4608) {
    int rel = blk - 4096; int b = rel >> 5, tb = rel & 31;
    transpose_body(rep + (size_t)b * 512 * 256,
                   repT + (size_t)b * 256 * 512, nullptr, 512,
                   (size_t)(tb >> 2) * 64, (size_t)(tb & 3) * 64, t, lTf);
  } else {
    int rel = blk - 4608;
    transpose_body(W, Wth, Wtl, 512, (size_t)(rel >> 2) * 64,
                   (size_t)(rel & 3) * 64, t, lTf);
  }
}

template<int APPLY_D>
__global__ __launch_bounds__(256) void ugemm_kernel(
    const float* __restrict__ X,
    const unsigned short* __restrict__ Wth, const unsigned short* __restrict__ Wtl,
    const float* __restrict__ Dv,
    unsigned short* __restrict__ Uh, unsigned short* __restrict__ Ul)
{
  __shared__ __align__(16) unsigned char smem[51200];
  ugemm_body<APPLY_D>(X, Wth, Wtl, Dv, Uh, Ul,
                      (size_t)blockIdx.x * 64, threadIdx.x, smem);
}

// ---------------------------------------------------------------------------
// Kernel 2 (dir 2): softmax over Q then @ rep.  [round-12 512-thread version]
// 8 waves (wr,wc), 64-row P-tile. Phase-1 pipeline: B (Uq) staged in 128-q
// halves, DOUBLE-BUFFERED, prefetch-to-regs before compute / ds_write after,
// ONE barrier per iteration. A (Up) frags in registers from L2 (k0 prefetch).
// Phase 2 FUSED over both halves: probs[64][520] in LDS, rT frags loaded
// once per k0 feed 8 MFMAs (acc2[4][2]).
// qcol(j) = (j>>1)*128 + wc*32 + (j&1)*16 + l15.
// If STORE_S: store p-masked S^T u16 (vs 32-row-tile col max) + colmaxP.
// ---------------------------------------------------------------------------
template<int STORE_S>
__global__ __launch_bounds__(512, 4) void dir2_kernel(
    const unsigned short* __restrict__ Uph, const unsigned short* __restrict__ Upl,
    const unsigned short* __restrict__ Uqh, const unsigned short* __restrict__ Uql,
    const unsigned short* __restrict__ repT, const unsigned char* __restrict__ qmask,
    const unsigned char* __restrict__ pmask, unsigned short* __restrict__ St,
    float* __restrict__ colmaxP, float* __restrict__ out)
{
  __shared__ __align__(16) unsigned char smem[68608];
  unsigned short* probs = (unsigned short*)smem;               // [64][520] overlay
  float* smax = (float*)(smem + 66560);                        // [4][64]
  float* ssum = (float*)(smem + 67584);                        // [4][64]

  const int id = blockIdx.x;                     // 1024 = 16b x 64 ptiles
  const int b  = (id & 7) | ((id >> 9) << 3);    // batch -> XCD swizzle
  const int p0 = ((id >> 3) & 63) * 64;
  const int t = threadIdx.x;
  const int w = t >> 6, l = t & 63;
  const int wr = w >> 2, wc = w & 3;             // wave p-half / q-group
  const int l15 = l & 15, lg = l >> 4, kr = lg * 8;
  const int srow = t >> 2, sc = (t & 3) * 8;     // B staging row/col

  const unsigned short* UqBh = Uqh + (size_t)b * 512 * 256;
  const unsigned short* UqBl = Uql + (size_t)b * 512 * 256;
  const size_t aoff = ((size_t)b * 4096 + p0 + wr * 32 + l15) * 256 + kr;
  const unsigned short* pAh0 = Uph + aoff;
  const unsigned short* pAh1 = pAh0 + 16 * 256;
  const unsigned short* pAl0 = Upl + aoff;
  const unsigned short* pAl1 = pAl0 + 16 * 256;

  auto lbh = [&](int buf) { return (unsigned short*)(smem + buf * 20480); };
  auto lbl = [&](int buf) { return (unsigned short*)(smem + buf * 20480 + 10240); };

  f32x4 acc[2][8] = {};
  short8v cah0, cah1, cal0, cal1;
  short8v nah0, nah1, nal0, nal1;
  short8v rh, rl;

  cah0 = *(const short8v*)&pAh0[0];
  cah1 = *(const short8v*)&pAh1[0];
  cal0 = *(const short8v*)&pAl0[0];
  cal1 = *(const short8v*)&pAl1[0];
  {
    size_t g = (size_t)srow * 256 + sc;
    rh = *(const short8v*)&UqBh[g];
    rl = *(const short8v*)&UqBl[g];
  }
  *(short8v*)&lbh(0)[srow * 40 + sc] = rh;
  *(short8v*)&lbl(0)[srow * 40 + sc] = rl;
  __syncthreads();

  for (int k0 = 0; k0 < 8; ++k0) {
#pragma unroll
    for (int qh = 0; qh < 4; ++qh) {
      const int cur = qh & 1;
      const bool last = (k0 == 7) && (qh == 3);
      if (!last) {
        int nk0 = (qh == 3) ? k0 + 1 : k0;
        int nqh = (qh == 3) ? 0 : qh + 1;
        size_t g = (size_t)(nqh * 128 + srow) * 256 + nk0 * 32 + sc;
        rh = *(const short8v*)&UqBh[g];
        rl = *(const short8v*)&UqBl[g];
      }
      if (qh == 3 && k0 < 7) {
        size_t ao = (size_t)(k0 + 1) * 32;
        nah0 = *(const short8v*)&pAh0[ao];
        nah1 = *(const short8v*)&pAh1[ao];
        nal0 = *(const short8v*)&pAl0[ao];
        nal1 = *(const short8v*)&pAl1[ao];
      }
      const unsigned short* bhp = lbh(cur);
      const unsigned short* blp = lbl(cur);
#pragma unroll
      for (int qi = 0; qi < 2; ++qi) {
        int rr = (wc * 32 + qi * 16 + l15) * 40 + kr;
        short8v bh = *(const short8v*)&bhp[rr];
        short8v bl = *(const short8v*)&blp[rr];
        int j = qh * 2 + qi;
        acc[0][j] = MFMA16(cah0, bh, acc[0][j]);
        acc[0][j] = MFMA16(cah0, bl, acc[0][j]);
        acc[0][j] = MFMA16(cal0, bh, acc[0][j]);
        acc[1][j] = MFMA16(cah1, bh, acc[1][j]);
        acc[1][j] = MFMA16(cah1, bl, acc[1][j]);
        acc[1][j] = MFMA16(cal1, bh, acc[1][j]);
      }
      if (!last) {
        *(short8v*)&lbh(cur ^ 1)[srow * 40 + sc] = rh;
        *(short8v*)&lbl(cur ^ 1)[srow * 40 + sc] = rl;
      }
      if (qh == 3 && k0 < 7) { cah0 = nah0; cah1 = nah1; cal0 = nal0; cal1 = nal1; }
      __syncthreads();
    }
  }
  if (STORE_S) {
    const unsigned char* pmk = pmask + (size_t)b * 4096 + p0 + wr * 32;
    unsigned int pmw0 = *(const unsigned int*)&pmk[lg * 4];
    unsigned int pmw1 = *(const unsigned int*)&pmk[16 + lg * 4];
#pragma unroll
    for (int j = 0; j < 8; ++j) {
      int qcol = ((j >> 1) << 7) + wc * 32 + ((j & 1) << 4) + l15;
      float a0[4], a1[4];
      float cm = -1e30f;
#pragma unroll
      for (int r = 0; r < 4; ++r) {
        a0[r] = ((pmw0 >> (8 * r)) & 0xFFu) ? -1e30f : acc[0][j][r];
        a1[r] = ((pmw1 >> (8 * r)) & 0xFFu) ? -1e30f : acc[1][j][r];
        cm = fmaxf(cm, fmaxf(a0[r], a1[r]));
      }
      cm = fmaxf(cm, __shfl_xor(cm, 16));
      cm = fmaxf(cm, __shfl_xor(cm, 32));
      us4 e0, e1;
#pragma unroll
      for (int r = 0; r < 4; ++r) {
        e0[r] = enc16(a0[r], cm);
        e1[r] = enc16(a1[r], cm);
      }
      size_t sb = ((size_t)b * 512 + qcol) * 4096 + p0 + wr * 32 + lg * 4;
      *(us4*)&St[sb]      = e0;
      *(us4*)&St[sb + 16] = e1;
      if (l < 16)
        colmaxP[((size_t)b * 128 + (p0 >> 5) + wr) * 512 + qcol] = cm;
    }
  }
  const unsigned char* qm = qmask + (size_t)b * 512;
#pragma unroll
  for (int j = 0; j < 8; ++j) {
    int qcol = ((j >> 1) << 7) + wc * 32 + ((j & 1) << 4) + l15;
    if (qm[qcol]) {
#pragma unroll
      for (int mi = 0; mi < 2; ++mi)
#pragma unroll
        for (int r = 0; r < 4; ++r) acc[mi][j][r] = -1e30f;
    }
  }
#pragma unroll
  for (int mi = 0; mi < 2; ++mi)
#pragma unroll
    for (int r = 0; r < 4; ++r) {
      float v = acc[mi][0][r];
#pragma unroll
      for (int j = 1; j < 8; ++j) v = fmaxf(v, acc[mi][j][r]);
      v = fmaxf(v, __shfl_xor(v, 1)); v = fmaxf(v, __shfl_xor(v, 2));
      v = fmaxf(v, __shfl_xor(v, 4)); v = fmaxf(v, __shfl_xor(v, 8));
      if (l15 == 0) smax[wc * 64 + wr * 32 + mi * 16 + lg * 4 + r] = v;
    }
  __syncthreads();          // B1
  float Mx[2][4];
#pragma unroll
  for (int mi = 0; mi < 2; ++mi)
#pragma unroll
    for (int r = 0; r < 4; ++r) {
      int row = wr * 32 + mi * 16 + lg * 4 + r;
      Mx[mi][r] = fmaxf(fmaxf(smax[row], smax[64 + row]),
                        fmaxf(smax[128 + row], smax[192 + row]));
    }
  float rs[2][4] = {};
#pragma unroll
  for (int mi = 0; mi < 2; ++mi)
#pragma unroll
    for (int j = 0; j < 8; ++j)
#pragma unroll
      for (int r = 0; r < 4; ++r) {
        float ev = __expf(acc[mi][j][r] - Mx[mi][r]);
        acc[mi][j][r] = ev;
        rs[mi][r] += ev;
      }
#pragma unroll
  for (int mi = 0; mi < 2; ++mi)
#pragma unroll
    for (int r = 0; r < 4; ++r) {
      float v = rs[mi][r];
      v += __shfl_xor(v, 1); v += __shfl_xor(v, 2);
      v += __shfl_xor(v, 4); v += __shfl_xor(v, 8);
      if (l15 == 0) ssum[wc * 64 + wr * 32 + mi * 16 + lg * 4 + r] = v;
    }
#pragma unroll
  for (int mi = 0; mi < 2; ++mi)
#pragma unroll
    for (int j = 0; j < 8; ++j) {
      int qcol = ((j >> 1) << 7) + wc * 32 + ((j & 1) << 4) + l15;
#pragma unroll
      for (int r = 0; r < 4; ++r)
        probs[(wr * 32 + mi * 16 + lg * 4 + r) * 520 + qcol] = f2bf(acc[mi][j][r]);
    }
  __syncthreads();          // B2
  const unsigned short* rT = repT + (size_t)b * 131072;
  float invv[4][4];
#pragma unroll
  for (int mi = 0; mi < 4; ++mi)
#pragma unroll
    for (int r = 0; r < 4; ++r) {
      int row = mi * 16 + lg * 4 + r;
      invv[mi][r] = 1.0f / (ssum[row] + ssum[64 + row] +
                            ssum[128 + row] + ssum[192 + row]);
    }
  f32x4 acc2[4][2] = {};
  const unsigned short* rTb = rT + (size_t)(w * 32 + l15) * 512 + kr;
  short8v cb0 = *(const short8v*)(rTb);
  short8v cb1 = *(const short8v*)(rTb + 16 * 512);
  for (int k0 = 0; k0 < 512; k0 += 32) {
    int kn = (k0 + 32) & 511;
    short8v nb0 = *(const short8v*)(rTb + kn);
    short8v nb1 = *(const short8v*)(rTb + 16 * 512 + kn);
    short8v a0 = *(const short8v*)&probs[(l15) * 520 + k0 + kr];
    short8v a1 = *(const short8v*)&probs[(16 + l15) * 520 + k0 + kr];
    short8v a2 = *(const short8v*)&probs[(32 + l15) * 520 + k0 + kr];
    short8v a3 = *(const short8v*)&probs[(48 + l15) * 520 + k0 + kr];
    acc2[0][0] = MFMA16(a0, cb0, acc2[0][0]);
    acc2[1][0] = MFMA16(a1, cb0, acc2[1][0]);
    acc2[2][0] = MFMA16(a2, cb0, acc2[2][0]);
    acc2[3][0] = MFMA16(a3, cb0, acc2[3][0]);
    acc2[0][1] = MFMA16(a0, cb1, acc2[0][1]);
    acc2[1][1] = MFMA16(a1, cb1, acc2[1][1]);
    acc2[2][1] = MFMA16(a2, cb1, acc2[2][1]);
    acc2[3][1] = MFMA16(a3, cb1, acc2[3][1]);
    cb0 = nb0; cb1 = nb1;
  }
#pragma unroll
  for (int mi = 0; mi < 4; ++mi)
#pragma unroll
    for (int di = 0; di < 2; ++di)
#pragma unroll
      for (int r = 0; r < 4; ++r) {
        int row = p0 + mi * 16 + lg * 4 + r;
        int col = w * 32 + di * 16 + l15;
        out[((size_t)b * 4096 + row) * 256 + col] = acc2[mi][di][r] * invv[mi][r];
      }
}

// ---------------------------------------------------------------------------
// Kernel (dir 1): O_q partial = exp(S^T - M) @ rep_p over a 1024-p chunk.
// Grid 1024 = 16b x 16qt x 4chunk. Pipelined (V dbuf in regs, St 1 tile
// early). ONE barrier per tile. s_setprio around MFMA cluster (T5).
// ---------------------------------------------------------------------------
__global__ __launch_bounds__(256) void dir1_pv(
    const unsigned short* __restrict__ St, const float* __restrict__ colmaxP,
    const unsigned short* __restrict__ repTp,
    float* __restrict__ accP, float* __restrict__ mlP)
{
  __shared__ unsigned short lAe[2][32 * 72];
  const int id = blockIdx.x;
  const int xcd = id & 7, r0 = id >> 3;
  const int b = xcd * 2 + (r0 >> 6);
  const int rem = r0 & 63;
  const int qt = rem >> 2, ch = rem & 3;
  const int q0 = qt * 32, pbeg = ch * 1024;
  const int pi = (b * 16 + qt) * 4 + ch;
  const int NT = 16;

  const int t = threadIdx.x;
  const int w = t >> 6, l = t & 63;
  const int l15 = l & 15, lg = l >> 4, kr = lg * 8;
  const int srow = t >> 3, sp = (t & 7) * 8;

  const float* cmq = colmaxP + (size_t)b * 128 * 512 + q0 + srow;
  float mq_s;
  {
    const int part = t & 7;
    float m = -1e30f;
#pragma unroll
    for (int j = 0; j < 16; ++j)
      m = fmaxf(m, cmq[(size_t)(part + j * 8) * 512]);
    m = fmaxf(m, __shfl_xor(m, 1));
    m = fmaxf(m, __shfl_xor(m, 2));
    m = fmaxf(m, __shfl_xor(m, 4));
    mq_s = m;
  }
  const unsigned short* Sb = St + ((size_t)b * 512 + q0 + srow) * 4096;
  const unsigned short* vtb = repTp + ((size_t)b * 256 + w * 64 + l15) * 4096;
  float rsum = 0.f;
  f32x4 acc[2][4] = {};
  us8v u; float cmv;
  short8v bvA[2][4], bvB[2][4];

  auto STAGE_LOAD = [&](int tile) {
    int pelem = pbeg + tile * 64 + sp;
    u = *(const us8v*)(Sb + pelem);
    cmv = cmq[(size_t)(pelem >> 5) * 512];
  };
  auto STAGE_FINISH = [&](int buf) {
    float base = cmv - 20.f - mq_s;
    short8v pk;
#pragma unroll
    for (int e = 0; e < 8; ++e) {
      float ev = __expf((float)u[e] * (1.f / 3276.8f) + base);
      rsum += ev;
      pk[e] = (short)f2bf(ev);
    }
    *(short8v*)&lAe[buf][srow * 72 + sp] = pk;
  };
  auto BV_LOAD = [&](int tile, short8v (&bv)[2][4]) {
    int p0v = pbeg + tile * 64;
#pragma unroll
    for (int ks = 0; ks < 2; ++ks)
#pragma unroll
      for (int di = 0; di < 4; ++di)
        bv[ks][di] = *(const short8v*)&vtb[(size_t)(di * 16) * 4096 + p0v + ks * 32 + kr];
  };
  auto COMPUTE = [&](int buf, short8v (&bv)[2][4]) {
    __builtin_amdgcn_s_setprio(1);
#pragma unroll
    for (int ks = 0; ks < 2; ++ks) {
      short8v pa0 = *(const short8v*)&lAe[buf][l15 * 72 + ks * 32 + kr];
      short8v pa1 = *(const short8v*)&lAe[buf][(16 + l15) * 72 + ks * 32 + kr];
#pragma unroll
      for (int di = 0; di < 4; ++di) {
        acc[0][di] = MFMA16(pa0, bv[ks][di], acc[0][di]);
        acc[1][di] = MFMA16(pa1, bv[ks][di], acc[1][di]);
      }
    }
    __builtin_amdgcn_s_setprio(0);
  };

  STAGE_LOAD(0);
  BV_LOAD(0, bvA);
  STAGE_FINISH(0);
  STAGE_LOAD(1);
  __syncthreads();

#pragma unroll 1
  for (int tt = 0; tt < NT; tt += 2) {
    const bool has1 = (tt + 1 < NT), has2 = (tt + 2 < NT), has3 = (tt + 3 < NT);
    if (has1) BV_LOAD(tt + 1, bvB);
    COMPUTE(0, bvA);
    if (has1) STAGE_FINISH(1);
    if (has2) STAGE_LOAD(tt + 2);
    __syncthreads();
    if (has1) {
      if (has2) BV_LOAD(tt + 2, bvA);
      COMPUTE(1, bvB);
      if (has2) STAGE_FINISH(0);
      if (has3) STAGE_LOAD(tt + 3);
      __syncthreads();
    }
  }

  rsum += __shfl_xor(rsum, 1);
  rsum += __shfl_xor(rsum, 2);
  rsum += __shfl_xor(rsum, 4);
  if ((t & 7) == 0) mlP[(size_t)pi * 32 + srow] = rsum;

  float* ab = accP + (size_t)pi * 32 * 256;
#pragma unroll
  for (int mi = 0; mi < 2; ++mi)
#pragma unroll
    for (int di = 0; di < 4; ++di)
#pragma unroll
      for (int r = 0; r < 4; ++r) {
        int row = mi * 16 + lg * 4 + r;
        int col = w * 64 + di * 16 + l15;
        ab[(size_t)row * 256 + col] = acc[mi][di][r];
      }
}

// ---------------------------------------------------------------------------
// Kernel: merge 4 sum-partials (shared true max -> plain sums) -> outq.
// ---------------------------------------------------------------------------
__global__ __launch_bounds__(256) void merge4_kernel(
    const float* __restrict__ accP, const float* __restrict__ mlP,
    float* __restrict__ outq)
{
  const int g = blockIdx.x * 256 + threadIdx.x;
  const int row = g >> 6;
  const int d0 = (g & 63) * 4;
  const int b = row >> 9, q = row & 511;
  const int qt = q >> 5, ri = q & 31;
  const int pbase = (b * 16 + qt) * 4;
  float s = 0.f;
  float4v o = {0.f, 0.f, 0.f, 0.f};
#pragma unroll
  for (int c = 0; c < 4; ++c) {
    s += mlP[(size_t)(pbase + c) * 32 + ri];
    float4v a = *(const float4v*)&accP[((size_t)(pbase + c) * 32 + ri) * 256 + d0];
#pragma unroll
    for (int k = 0; k < 4; ++k) o[k] += a[k];
  }
  float inv = 1.0f / s;
#pragma unroll
  for (int k = 0; k < 4; ++k) o[k] *= inv;
  *(float4v*)&outq[(size_t)row * 256 + d0] = o;
}

// ---------------------------------------------------------------------------
// FALLBACK (small ws): round-3 split-K flash dir1 + LSE merge.
// ---------------------------------------------------------------------------
__global__ __launch_bounds__(256) void dir1_partial(
    const unsigned short* __restrict__ Uph, const unsigned short* __restrict__ Upl,
    const unsigned short* __restrict__ Uqh, const unsigned short* __restrict__ Uql,
    const unsigned short* __restrict__ repTp, const unsigned char* __restrict__ pmask,
    float* __restrict__ accP, float* __restrict__ mlP)
{
  __shared__ __align__(16) unsigned char smem[39424];
  unsigned short* lAh = (unsigned short*)smem;
  unsigned short* lAl = (unsigned short*)(smem + 16896);
  unsigned short* lP  = (unsigned short*)(smem + 33792);
  float* smax = (float*)(smem + 38400);
  float* ssum = (float*)(smem + 38912);

  const int id  = blockIdx.x;
  const int xcd = id & 7, rr0 = id >> 3;
  const int b   = xcd * 2 + (rr0 >> 6);
  const int rem = rr0 & 63;
  const int qt  = rem >> 2, ch = rem & 3;
  const int q0  = qt * 32;
  const int pbeg = ch * 1024;
  const int pi  = (b * 16 + qt) * 4 + ch;

  const int t = threadIdx.x;
  const int w = t >> 6, l = t & 63;
  const int l15 = l & 15, lg = l >> 4, kr = lg * 8;

#pragma unroll
  for (int j = 0; j < 4; ++j) {
    int idx = j * 256 + t;
    int row = idx >> 5, c = (idx & 31) * 8;
    size_t g = ((size_t)b * 512 + q0 + row) * 256 + c;
    *(short8v*)&lAh[row * 264 + c] = *(const short8v*)&Uqh[g];
    *(short8v*)&lAl[row * 264 + c] = *(const short8v*)&Uql[g];
  }
  float m_r[2][4], l_r[2][4];
#pragma unroll
  for (int mi = 0; mi < 2; ++mi)
#pragma unroll
    for (int r = 0; r < 4; ++r) { m_r[mi][r] = -1e30f; l_r[mi][r] = 0.f; }
  f32x4 accO[2][4] = {};
  const size_t upoff = ((size_t)b * 4096 + w * 16 + l15) * 256;
  const unsigned short* upbh = Uph + upoff;
  const unsigned short* upbl = Upl + upoff;
  const unsigned short* vtb = repTp + (size_t)b * 1048576;
  const unsigned char* pm = pmask + (size_t)b * 4096;
  __syncthreads();

  for (int p0 = pbeg; p0 < pbeg + 1024; p0 += 64) {
    f32x4 s[2] = {};
#pragma unroll
    for (int k0 = 0; k0 < 256; k0 += 32) {
      short8v ah0 = *(const short8v*)&lAh[l15 * 264 + k0 + kr];
      short8v ah1 = *(const short8v*)&lAh[(16 + l15) * 264 + k0 + kr];
      short8v al0 = *(const short8v*)&lAl[l15 * 264 + k0 + kr];
      short8v al1 = *(const short8v*)&lAl[(16 + l15) * 264 + k0 + kr];
      short8v bvh = *(const short8v*)&upbh[(size_t)p0 * 256 + k0 + kr];
      short8v bvl = *(const short8v*)&upbl[(size_t)p0 * 256 + k0 + kr];
      s[0] = MFMA16(ah0, bvh, s[0]);
      s[0] = MFMA16(ah0, bvl, s[0]);
      s[0] = MFMA16(al0, bvh, s[0]);
      s[1] = MFMA16(ah1, bvh, s[1]);
      s[1] = MFMA16(ah1, bvl, s[1]);
      s[1] = MFMA16(al1, bvh, s[1]);
    }
    if (pm[p0 + w * 16 + l15]) {
#pragma unroll
      for (int mi = 0; mi < 2; ++mi)
#pragma unroll
        for (int r = 0; r < 4; ++r) s[mi][r] = -1e30f;
    }
#pragma unroll
    for (int mi = 0; mi < 2; ++mi)
#pragma unroll
      for (int r = 0; r < 4; ++r) {
        float v = s[mi][r];
        v = fmaxf(v, __shfl_xor(v, 1)); v = fmaxf(v, __shfl_xor(v, 2));
        v = fmaxf(v, __shfl_xor(v, 4)); v = fmaxf(v, __shfl_xor(v, 8));
        if (l15 == 0) smax[w * 32 + mi * 16 + lg * 4 + r] = v;
      }
    __syncthreads();
    float mnew[2][4], fsc[2][4], e[2][4];
#pragma unroll
    for (int mi = 0; mi < 2; ++mi)
#pragma unroll
      for (int r = 0; r < 4; ++r) {
        int row = mi * 16 + lg * 4 + r;
        float tm = fmaxf(fmaxf(smax[row], smax[32 + row]),
                         fmaxf(smax[64 + row], smax[96 + row]));
        float mn = fmaxf(m_r[mi][r], tm);
        mnew[mi][r] = mn;
        fsc[mi][r] = __expf(m_r[mi][r] - mn);
        e[mi][r] = __expf(s[mi][r] - mn);
      }
#pragma unroll
    for (int mi = 0; mi < 2; ++mi)
#pragma unroll
      for (int r = 0; r < 4; ++r) {
        float v = e[mi][r];
        v += __shfl_xor(v, 1); v += __shfl_xor(v, 2);
        v += __shfl_xor(v, 4); v += __shfl_xor(v, 8);
        if (l15 == 0) ssum[w * 32 + mi * 16 + lg * 4 + r] = v;
        lP[(mi * 16 + lg * 4 + r) * 72 + w * 16 + l15] = f2bf(e[mi][r]);
      }
    __syncthreads();
#pragma unroll
    for (int mi = 0; mi < 2; ++mi)
#pragma unroll
      for (int r = 0; r < 4; ++r) {
        int row = mi * 16 + lg * 4 + r;
        float ts = ssum[row] + ssum[32 + row] + ssum[64 + row] + ssum[96 + row];
        l_r[mi][r] = l_r[mi][r] * fsc[mi][r] + ts;
        m_r[mi][r] = mnew[mi][r];
      }
#pragma unroll
    for (int mi = 0; mi < 2; ++mi)
#pragma unroll
      for (int di = 0; di < 4; ++di)
#pragma unroll
        for (int r = 0; r < 4; ++r) accO[mi][di][r] *= fsc[mi][r];
#pragma unroll
    for (int ks = 0; ks < 64; ks += 32) {
      short8v pa0 = *(const short8v*)&lP[l15 * 72 + ks + kr];
      short8v pa1 = *(const short8v*)&lP[(16 + l15) * 72 + ks + kr];
#pragma unroll
      for (int di = 0; di < 4; ++di) {
        short8v bv = *(const short8v*)&vtb[(size_t)(w * 64 + di * 16 + l15) * 4096 + p0 + ks + kr];
        accO[0][di] = MFMA16(pa0, bv, accO[0][di]);
        accO[1][di] = MFMA16(pa1, bv, accO[1][di]);
      }
    }
  }
  float* ab = accP + (size_t)pi * 32 * 256;
#pragma unroll
  for (int mi = 0; mi < 2; ++mi)
#pragma unroll
    for (int di = 0; di < 4; ++di)
#pragma unroll
      for (int r = 0; r < 4; ++r) {
        int row = mi * 16 + lg * 4 + r;
        int col = w * 64 + di * 16 + l15;
        ab[(size_t)row * 256 + col] = accO[mi][di][r];
      }
  if (w == 0 && l15 == 0) {
#pragma unroll
    for (int mi = 0; mi < 2; ++mi)
#pragma unroll
      for (int r = 0; r < 4; ++r) {
        int row = mi * 16 + lg * 4 + r;
        mlP[((size_t)pi * 32 + row) * 2 + 0] = m_r[mi][r];
        mlP[((size_t)pi * 32 + row) * 2 + 1] = l_r[mi][r];
      }
  }
}

__global__ __launch_bounds__(256) void merge_kernel(
    const float* __restrict__ accP, const float* __restrict__ mlP,
    float* __restrict__ outq)
{
  const int g = blockIdx.x * 256 + threadIdx.x;
  const int row = g >> 6;
  const int d0 = (g & 63) * 4;
  const int b = row >> 9, q = row & 511;
  const int qt = q >> 5, ri = q & 31;
  const int pbase = (b * 16 + qt) * 4;
  float m[4], lv[4];
  float M = -1e30f;
#pragma unroll
  for (int c = 0; c < 4; ++c) {
    m[c]  = mlP[((size_t)(pbase + c) * 32 + ri) * 2 + 0];
    lv[c] = mlP[((size_t)(pbase + c) * 32 + ri) * 2 + 1];
    M = fmaxf(M, m[c]);
  }
  float s = 0.f;
  float4v o = {0.f, 0.f, 0.f, 0.f};
#pragma unroll
  for (int c = 0; c < 4; ++c) {
    float e = __expf(m[c] - M);
    s += e * lv[c];
    float4v a = *(const float4v*)&accP[((size_t)(pbase + c) * 32 + ri) * 256 + d0];
#pragma unroll
    for (int k = 0; k < 4; ++k) o[k] += e * a[k];
  }
  float inv = 1.0f / s;
#pragma unroll
  for (int k = 0; k < 4; ++k) o[k] *= inv;
  *(float4v*)&outq[(size_t)row * 256 + d0] = o;
}

// ---------------------------------------------------------------------------
extern "C" void kernel_launch(void* const* d_in, const int* in_sizes, int n_in,
                              void* d_out, int out_size, void* d_ws, size_t ws_size,
                              hipStream_t stream) {
  (void)in_sizes; (void)n_in; (void)out_size;
  const float* passage        = (const float*)d_in[0];
  const unsigned char* p_mask = (const unsigned char*)d_in[1];
  const float* question       = (const float*)d_in[2];
  const unsigned char* q_mask = (const unsigned char*)d_in[3];
  const float* rep            = (const float*)d_in[4];
  const float* rep_p          = (const float*)d_in[5];
  const float* W              = (const float*)d_in[6];
  const float* Dv             = (const float*)d_in[7];

  unsigned short* Wth   = (unsigned short*)d_ws;           // [256][512]
  unsigned short* Wtl   = Wth   + 131072;
  unsigned short* repT  = Wtl   + 131072;                  // [16][256][512]
  unsigned short* repTp = repT  + 2097152;                 // [16][256][4096]
  unsigned short* Uqh   = repTp + 16777216;                // [16*512][256]
  unsigned short* Uql   = Uqh   + 2097152;
  unsigned short* Uph   = Uql   + 2097152;                 // [16*4096][256]
  unsigned short* Upl   = Uph   + 16777216;
  // big-ws extras (beyond the 108.5 MB above):
  unsigned short* StU = (unsigned short*)((char*)d_ws + 113770496ULL); // [16][512][4096] u16
  float* colmaxP      = (float*)((char*)d_ws + 180879360ULL);          // [16][128][512]
  const size_t NEEDED = 185073664ULL;

  float* out  = (float*)d_out;                             // [16,4096,256]
  float* outq = out + (size_t)16 * 4096 * 256;             // [16,512,256]

  if (ws_size >= NEEDED) {
    // S-once path; prep fused; dir2 = round-12 512-thread version.
    float* accP4 = (float*)Uph;          // 33.5 MB, Up dead after dir2
    float* mlP4  = (float*)Uqh;          // 128 KB, Uq dead after dir2
    transpose_w<<<32, 256, 0, stream>>>(W, Wth, Wtl);
    prep_mega<<<5760, 256, 0, stream>>>(passage, question, rep, rep_p,
                                        Wth, Wtl, Dv, Uph, Upl, Uqh, Uql,
                                        repT, repTp);
    dir2_kernel<1><<<1024, 512, 0, stream>>>(Uph, Upl, Uqh, Uql, repT,
                                             q_mask, p_mask, StU, colmaxP, out);
    dir1_pv<<<1024, 256, 0, stream>>>(StU, colmaxP, repTp, accP4, mlP4);
    merge4_kernel<<<2048, 256, 0, stream>>>(accP4, mlP4, outq);
  } else {
    // fallback: round-3 split-K flash (accP in out region, before dir2)
    float* accP = out;
    float* mlP  = (float*)Wth;
    transpose_all<<<4640, 256, 0, stream>>>(W, rep, rep_p, Wth, Wtl, repT, repTp);
    ugemm_kernel<0><<<1024, 256, 0, stream>>>(passage,  Wth, Wtl, nullptr, Uph, Upl);
    ugemm_kernel<1><<<128,  256, 0, stream>>>(question, Wth, Wtl, Dv,      Uqh, Uql);
    dir1_partial<<<1024, 256, 0, stream>>>(Uph, Upl, Uqh, Uql, repTp, p_mask, accP, mlP);
    merge_kernel<<<2048, 256, 0, stream>>>(accP, mlP, outq);
    dir2_kernel<0><<<1024, 512, 0, stream>>>(Uph, Upl, Uqh, Uql, repT,
                                             q_mask, nullptr, nullptr, nullptr, out);
  }
}